// Round 11
// baseline (215.466 us; speedup 1.0000x reference)
//
#include <hip/hip_runtime.h>
#include <hip/hip_bf16.h>
#include <math.h>

#define T_SEQ 4096
#define EMB   1024
#define NH    8
#define HD    128
#define HALF  64

typedef __hip_bfloat16 bf16;
typedef __attribute__((ext_vector_type(8))) short short8;
typedef __attribute__((ext_vector_type(4))) short short4v;
typedef __attribute__((ext_vector_type(4))) float float4v;
typedef __attribute__((ext_vector_type(4))) unsigned int uint4v;

static __device__ __forceinline__ float b2f(bf16 v) { return __bfloat162float(v); }
static __device__ __forceinline__ bf16  f2b(float v) { return __float2bfloat16(v); }
static __device__ __forceinline__ short f2bs(float v) {
    bf16 h = __float2bfloat16(v); short s; __builtin_memcpy(&s, &h, 2); return s;
}
static __device__ __forceinline__ unsigned pk2(float a, float b) {
    return (unsigned)(unsigned short)f2bs(a) | ((unsigned)(unsigned short)f2bs(b) << 16);
}
// async global->LDS, 16B per lane; lds base must be wave-uniform
static __device__ __forceinline__ void gload16(const short* g, short* l) {
    __builtin_amdgcn_global_load_lds((__attribute__((address_space(1))) void*)g,
                                     (__attribute__((address_space(3))) void*)l, 16, 0, 0);
}

// ---------------------------------------------------------------------------
// Converters (R7/R9 verbatim): z<4 -> weight transpose; z==4 -> x fp32->bf16.
// The xb pre-pass is bandwidth compression (R8 fusion attempt regressed).
// ---------------------------------------------------------------------------
__global__ __launch_bounds__(256) void convert_all(
    const float* __restrict__ w0, const float* __restrict__ w1,
    const float* __restrict__ w2, const float* __restrict__ w3,
    const float* __restrict__ x,
    short* __restrict__ wbT, short* __restrict__ xb)
{
    const int tid = threadIdx.x;
    if (blockIdx.z == 4) {
        const int r0 = blockIdx.x * 64;
        const int c0 = blockIdx.y * 64;
        #pragma unroll
        for (int t = 0; t < 4; ++t) {
            int id = tid + t*256;
            int r = id >> 4, c4 = id & 15;
            float4 f = *(const float4*)(x + (size_t)(r0+r)*EMB + c0 + c4*4);
            short4v s = { f2bs(f.x), f2bs(f.y), f2bs(f.z), f2bs(f.w) };
            *(short4v*)(xb + (size_t)(r0+r)*EMB + c0 + c4*4) = s;
        }
        return;
    }
    if (blockIdx.x >= 16) return;
    const float* W = (blockIdx.z==0)?w0:(blockIdx.z==1)?w1:(blockIdx.z==2)?w2:w3;
    short* dst = wbT + (size_t)blockIdx.z * EMB * EMB;
    __shared__ float tile[64][65];
    const int k0 = blockIdx.x * 64;
    const int n0 = blockIdx.y * 64;
    #pragma unroll
    for (int t = 0; t < 4; ++t) {
        int id = tid + t*256;
        int r = id >> 4, c4 = id & 15;
        float4 f = *(const float4*)(W + (size_t)(k0+r)*EMB + n0 + c4*4);
        tile[r][c4*4+0]=f.x; tile[r][c4*4+1]=f.y; tile[r][c4*4+2]=f.z; tile[r][c4*4+3]=f.w;
    }
    __syncthreads();
    #pragma unroll
    for (int t = 0; t < 4; ++t) {
        int id = tid + t*256;
        int n = id >> 4, k4 = id & 15;
        short4v s;
        #pragma unroll
        for (int j = 0; j < 4; ++j) s[j] = f2bs(tile[k4*4+j][n]);
        *(short4v*)(dst + (size_t)(n0+n)*EMB + k0 + k4*4) = s;
    }
}

// ---------------------------------------------------------------------------
// qkv GEMM: 256x256 tile, 512 threads (8 waves = 4M x 2N; wave owns 64 rows
// x 128 cols = one head). 8-phase K-tile (BK=64), dbuf LDS (128 KB).
// R10 RACE FIX: in-order vmcnt retirement means waits depend on ISSUE
// ORDER. Steady-state per-tile issue order is A0,A1,A2,A3,B0,B2,B1,B3
// (p2 stages {B0,B2}, p3 {B1,B3}); R10's prologue staged B0,B1,B2,B3, so
// kt=0.p0's vmcnt(4) left B2 in flight while wc=1 waves read rows 128-191
// -> NaN race. Prologue now stages B in order 0,2,1,3 == steady state.
// Per-wave vmcnt ledger (2 loads/pair, in-order retire):
//   kt.p0 after issuing A01(kt+1): queue = [A0..A3,B0,B2,B1,B3](kt)+A01' =
//     10 -> vmcnt(4) retires A(kt) full + B0,B2(kt) (exactly what p0 reads:
//     A group wr; B rows {0-63}(wc=0) / {128-191}(wc=1)). 2-4 phase lead.
//   kt.p1 after issuing A23(kt+1): queue = [B1,B3(kt), A01',A23'] = 6 ->
//     vmcnt(4) retires B1,B3(kt) (p1 reads B rows {64-127}/{192-255}).
//   p2/p3: no wait. Tail kt=15: p0 vmcnt(2), p1 vmcnt(0).
// Barrier BEFORE each phase's ds_reads (makes per-wave vmcnt collective);
// end-of-tile barrier closes the dbuf WAR (reads of buf kt done before
// anyone stages kt+2 into the same parity).
// LDS layout: row = 8 x 16B units, phys = logical ^ (row&7), inverse on
// global src. Read: pu = ((ks*4+q)^(cl&7))*8.
// ---------------------------------------------------------------------------
#define QKV_MFMA_PHASE(KS, NHALF, LOADA)                                      \
    do {                                                                      \
        const int pu_ = (((KS)*4 + q) ^ (cl & 7)) * 8;                        \
        if (LOADA) {                                                          \
            _Pragma("unroll")                                                 \
            for (int mi_ = 0; mi_ < 4; ++mi_)                                 \
                af[mi_] = *(const short8*)&Ab[(arow + mi_*16 + cl)*64 + pu_]; \
        }                                                                     \
        short8 b0_ = *(const short8*)&Bb[(brow + ((NHALF)*4+0)*16 + cl)*64 + pu_]; \
        short8 b1_ = *(const short8*)&Bb[(brow + ((NHALF)*4+1)*16 + cl)*64 + pu_]; \
        short8 b2_ = *(const short8*)&Bb[(brow + ((NHALF)*4+2)*16 + cl)*64 + pu_]; \
        short8 b3_ = *(const short8*)&Bb[(brow + ((NHALF)*4+3)*16 + cl)*64 + pu_]; \
        asm volatile("s_waitcnt lgkmcnt(0)" ::: "memory");                    \
        __builtin_amdgcn_sched_barrier(0);                                    \
        __builtin_amdgcn_s_setprio(1);                                        \
        _Pragma("unroll")                                                     \
        for (int mi_ = 0; mi_ < 4; ++mi_) {                                   \
            acc[mi_][(NHALF)*4+0] = __builtin_amdgcn_mfma_f32_16x16x32_bf16(af[mi_], b0_, acc[mi_][(NHALF)*4+0], 0,0,0); \
            acc[mi_][(NHALF)*4+1] = __builtin_amdgcn_mfma_f32_16x16x32_bf16(af[mi_], b1_, acc[mi_][(NHALF)*4+1], 0,0,0); \
            acc[mi_][(NHALF)*4+2] = __builtin_amdgcn_mfma_f32_16x16x32_bf16(af[mi_], b2_, acc[mi_][(NHALF)*4+2], 0,0,0); \
            acc[mi_][(NHALF)*4+3] = __builtin_amdgcn_mfma_f32_16x16x32_bf16(af[mi_], b3_, acc[mi_][(NHALF)*4+3], 0,0,0); \
        }                                                                     \
        __builtin_amdgcn_s_setprio(0);                                        \
        __builtin_amdgcn_sched_barrier(0);                                    \
    } while (0)

__global__ __launch_bounds__(512, 2) void qkv_gemm_mfma(
    const short* __restrict__ xb, const short* __restrict__ wbT,
    const float* __restrict__ cosb, const float* __restrict__ sinb,
    const float* __restrict__ x, const float* __restrict__ ve,
    const float* __restrict__ wg,
    short* __restrict__ qb, short* __restrict__ kb, short* __restrict__ vt)
{
    __shared__ short As[2][256*64];    // 2 x 32 KB
    __shared__ short Bs[2][256*64];    // 2 x 32 KB  -> 128 KB staging
    __shared__ float gbuf[2][256];
    const int n0g = blockIdx.x * 256;
    const int m0  = blockIdx.y * 256;
    const int z   = n0g >> 10;
    const int ncol0 = n0g & 1023;
    const int tid = threadIdx.x;
    const int wv = tid >> 6, lane = tid & 63;
    const int wr = wv >> 1, wc = wv & 1;     // 4M x 2N wave grid
    const int cl = lane & 15, q = lane >> 4;
    const int h = (ncol0 >> 7) + wc;         // per-wave head
    const int lrow8 = lane >> 3;
    const int lunit = (lane & 7) ^ (lrow8 & 7);
    const int arow = wr * 64;                // + mi*16 + cl
    const int brow = wc * 128;               // + ni*16 + cl

    if (z == 2 && tid < 256) {      // per-row, per-head gates for v epilogue
        const float4* xr = (const float4*)(x + (size_t)(m0 + tid)*EMB);
        const int hb = ncol0 >> 7;
        float s0 = 0.f, s1 = 0.f;
        #pragma unroll
        for (int c4 = 0; c4 < 8; ++c4) {
            float4 f = xr[c4];
            s0 += f.x * wg[(c4*4+0)*NH + hb]   + f.y * wg[(c4*4+1)*NH + hb]
                + f.z * wg[(c4*4+2)*NH + hb]   + f.w * wg[(c4*4+3)*NH + hb];
            s1 += f.x * wg[(c4*4+0)*NH + hb+1] + f.y * wg[(c4*4+1)*NH + hb+1]
                + f.z * wg[(c4*4+2)*NH + hb+1] + f.w * wg[(c4*4+3)*NH + hb+1];
        }
        gbuf[0][tid] = 2.f / (1.f + __expf(-s0));
        gbuf[1][tid] = 2.f / (1.f + __expf(-s1));
    }
    __syncthreads();    // publish gbuf; full drain -> vmcnt==0 baseline
    __builtin_amdgcn_sched_barrier(0);

    // stage-group g covers rows g*64..g*64+63 (1 gload16/thread)
    auto stageA = [&](short* dst, int k0, int g) {
        int chunk = g*8 + wv;
        gload16(xb + (size_t)(m0 + chunk*8 + lrow8)*EMB + k0 + lunit*8, dst + chunk*512);
    };
    auto stageB = [&](short* dst, int k0, int g) {
        int chunk = g*8 + wv;
        gload16(wbT + (size_t)(n0g + chunk*8 + lrow8)*EMB + k0 + lunit*8, dst + chunk*512);
    };

    float4v acc[4][8];
    #pragma unroll
    for (int mi=0;mi<4;++mi)
        #pragma unroll
        for (int ni=0;ni<8;++ni) acc[mi][ni]=(float4v){0.f,0.f,0.f,0.f};

    // prologue: stage tile 0 into buf 0 in the SAME issue order as the
    // steady-state loop (A0,A1,A2,A3,B0,B2,B1,B3) so the kt=0 waits
    // retire exactly the groups the phases read (R10 race fix).
    #pragma unroll
    for (int g = 0; g < 4; ++g) stageA(As[0], 0, g);
    stageB(Bs[0], 0, 0); stageB(Bs[0], 0, 2);
    stageB(Bs[0], 0, 1); stageB(Bs[0], 0, 3);

    short8 af[4];
    for (int kt = 0; kt < 16; ++kt) {
        const short* Ab = As[kt & 1];
        const short* Bb = Bs[kt & 1];
        short* An = As[(kt & 1) ^ 1];
        short* Bn = Bs[(kt & 1) ^ 1];
        const int k1 = (kt + 1) * 64;
        const bool st = kt < 15;
        // ---- p0: stage A01(kt+1); wait A(kt)+B0,B2(kt) (>=2-phase lead)
        if (st) {
            stageA(An, k1, 0); stageA(An, k1, 1);
            asm volatile("s_waitcnt vmcnt(4)" ::: "memory");
        } else {
            asm volatile("s_waitcnt vmcnt(2)" ::: "memory");
        }
        __builtin_amdgcn_s_barrier();
        __builtin_amdgcn_sched_barrier(0);
        QKV_MFMA_PHASE(0, 0, 1);
        // ---- p1: stage A23(kt+1); wait B1,B3(kt) (2-phase lead)
        if (st) {
            stageA(An, k1, 2); stageA(An, k1, 3);
            asm volatile("s_waitcnt vmcnt(4)" ::: "memory");
        } else {
            asm volatile("s_waitcnt vmcnt(0)" ::: "memory");
        }
        __builtin_amdgcn_s_barrier();
        __builtin_amdgcn_sched_barrier(0);
        QKV_MFMA_PHASE(0, 1, 0);
        // ---- p2: stage B0,B2(kt+1); no wait (data already published)
        if (st) { stageB(Bn, k1, 0); stageB(Bn, k1, 2); }
        __builtin_amdgcn_s_barrier();
        __builtin_amdgcn_sched_barrier(0);
        QKV_MFMA_PHASE(1, 0, 1);
        // ---- p3: stage B1,B3(kt+1); no wait
        if (st) { stageB(Bn, k1, 1); stageB(Bn, k1, 3); }
        __builtin_amdgcn_s_barrier();
        __builtin_amdgcn_sched_barrier(0);
        QKV_MFMA_PHASE(1, 1, 0);
        __builtin_amdgcn_s_barrier();   // end-of-tile: all buf-kt reads done
    }

    if (z == 2) {   // v: add gate*ve, store transposed vt[h][d][t]
        #pragma unroll
        for (int mi=0;mi<4;++mi) {
            const int t0r = m0 + wr*64 + mi*16 + q*4;
            #pragma unroll
            for (int ni=0;ni<8;++ni) {
                const int d = ni*16 + cl;
                short4v ov;
                #pragma unroll
                for (int r=0;r<4;++r) {
                    const int t = t0r + r;
                    float v = acc[mi][ni][r]
                            + gbuf[wc][t - m0] * ve[(size_t)t*EMB + h*HD + d];
                    ov[r] = f2bs(v);
                }
                *(short4v*)(vt + (size_t)(h*HD + d)*T_SEQ + t0r) = ov;
            }
        }
        return;
    }
    // q/k: rope + rms in registers (pair (d,d+64) = (ni, ni+4))
    short* dstb = (z == 0) ? qb : kb;
    #pragma unroll
    for (int mi=0;mi<4;++mi) {
        #pragma unroll
        for (int r=0;r<4;++r) {
            const int t = m0 + wr*64 + mi*16 + q*4 + r;
            float y1[4], y2[4];
            float ss = 0.f;
            #pragma unroll
            for (int ni=0;ni<4;++ni) {
                const int d = ni*16 + cl;
                float c = cosb[(size_t)t*HALF + d];
                float s = sinb[(size_t)t*HALF + d];
                float x1 = acc[mi][ni][r];
                float x2 = acc[mi][ni+4][r];
                y1[ni] = x1*c + x2*s;
                y2[ni] = x2*c - x1*s;
                ss += y1[ni]*y1[ni] + y2[ni]*y2[ni];
            }
            ss += __shfl_xor(ss, 1);
            ss += __shfl_xor(ss, 2);
            ss += __shfl_xor(ss, 4);
            ss += __shfl_xor(ss, 8);
            const float rr = rsqrtf(ss * (1.0f/HD) + 1e-6f);
            short* dst = dstb + (size_t)t*EMB + h*HD;
            #pragma unroll
            for (int ni=0;ni<4;++ni) {
                dst[ni*16 + cl]        = f2bs(y1[ni]*rr);
                dst[ni*16 + cl + HALF] = f2bs(y2[ni]*rr);
            }
        }
    }
}

// ---------------------------------------------------------------------------
// MFMA GEMM: out[4096,1024] fp32 = yb(bf16) @ wpT^T. 128x64 tile -> 512
// blocks = 2/CU. ROUND-0 VERBATIM (2-barrier form).
// ---------------------------------------------------------------------------
__global__ __launch_bounds__(256) void proj_gemm_mfma(
    const short* __restrict__ yb, const short* __restrict__ wpT,
    float* __restrict__ out)
{
    __shared__ short As[128*32];    // 8 KB
    __shared__ short Bs[64*32];     // 4 KB
    const int n0 = blockIdx.x * 64;
    const int m0 = blockIdx.y * 128;
    const int tid = threadIdx.x;
    const int wv = tid >> 6, lane = tid & 63;
    const int cl = lane & 15, q = lane >> 4;
    const int lrow = lane >> 2;
    const int lcol = (lane & 3) * 8;
    float4v acc[2][4];
    #pragma unroll
    for (int mi=0;mi<2;++mi)
        #pragma unroll
        for (int ni=0;ni<4;++ni) acc[mi][ni]=(float4v){0.f,0.f,0.f,0.f};

    for (int k0 = 0; k0 < EMB; k0 += 32) {
        __syncthreads();
        #pragma unroll
        for (int t = 0; t < 2; ++t) {
            int chunk = wv*2 + t;
            gload16(yb + (size_t)(m0 + chunk*16 + lrow)*EMB + k0 + lcol, &As[chunk*512]);
        }
        gload16(wpT + (size_t)(n0 + wv*16 + lrow)*EMB + k0 + lcol, &Bs[wv*512]);
        __syncthreads();
        short8 af[2], bfr[4];
        #pragma unroll
        for (int mi=0;mi<2;++mi) af[mi]  = *(const short8*)&As[(wv*32+mi*16+cl)*32 + q*8];
        #pragma unroll
        for (int ni=0;ni<4;++ni) bfr[ni] = *(const short8*)&Bs[(ni*16+cl)*32 + q*8];
        #pragma unroll
        for (int mi=0;mi<2;++mi)
            #pragma unroll
            for (int ni=0;ni<4;++ni)
                acc[mi][ni] = __builtin_amdgcn_mfma_f32_16x16x32_bf16(af[mi], bfr[ni], acc[mi][ni], 0, 0, 0);
    }
    #pragma unroll
    for (int mi=0;mi<2;++mi)
        #pragma unroll
        for (int ni=0;ni<4;++ni)
            #pragma unroll
            for (int r=0;r<4;++r)
                out[(size_t)(m0+wv*32+mi*16+q*4+r)*EMB + n0 + ni*16+cl] = acc[mi][ni][r];
}

// ---------------------------------------------------------------------------
// Flash attention (R9 verbatim): swapped QK^T, in-register P via pack+shfl,
// double-buffered K/V LDS with one barrier per tile, setprio on MFMA.
// ---------------------------------------------------------------------------
__global__ __launch_bounds__(256) void attn_flash(
    const bf16* __restrict__ qbh, const bf16* __restrict__ kbh,
    const bf16* __restrict__ vth, bf16* __restrict__ ybh,
    const int* __restrict__ wptr)
{
    const short* qb = (const short*)qbh;
    const short* kb = (const short*)kbh;
    const short* vt = (const short*)vth;
    short* yb = (short*)ybh;

    __shared__ short Ks[2][64*136];
    __shared__ short Vs[2][128*72];

    int W = *wptr; W = min(max(W, 1), 1024);
    const int h  = blockIdx.x;
    const int i0 = blockIdx.y * 64;
    const int tid  = threadIdx.x;
    const int wv   = tid >> 6;
    const int lane = tid & 63;
    const int cl   = lane & 15;
    const int q    = lane >> 4;
    const int m0   = wv * 16;
    const float scale = 0.08838834764831845f;

    short8 qa[4];
    {
        const short* qbase = qb + (size_t)(i0 + m0 + cl) * EMB + h*HD + q*8;
        #pragma unroll
        for (int ks = 0; ks < 4; ++ks)
            qa[ks] = *(const short8*)(qbase + ks*32);
    }

    float4v o[8];
    #pragma unroll
    for (int n = 0; n < 8; ++n) o[n] = (float4v){0.f,0.f,0.f,0.f};
    float lsum = 0.f;

    const int lo_key  = i0 - W + 1;
    const int jt_start = lo_key > 0 ? (lo_key >> 6) : 0;
    const int jt_end   = i0 >> 6;

    const int kkey[4] = { (tid+0)>>4, (tid+256)>>4, (tid+512)>>4, (tid+768)>>4 };
    const int kc16 = tid & 15;
    const int vd[4] = { (tid+0)>>3, (tid+256)>>3, (tid+512)>>3, (tid+768)>>3 };
    const int vc8 = tid & 7;

    const int src0 = cl + ((lane >> 4) & 1) * 32;
    const int src1 = src0 + 16;
    const bool hi  = (lane & 32) != 0;

    short8 kreg[4], vreg[4];
    {
        const int j0 = jt_start << 6;
        #pragma unroll
        for (int kk = 0; kk < 4; ++kk) {
            kreg[kk] = *(const short8*)(kb + (size_t)(j0+kkey[kk])*EMB + h*HD + kc16*8);
            vreg[kk] = *(const short8*)(vt + (size_t)(h*HD + vd[kk])*T_SEQ + j0 + vc8*8);
        }
    }

    for (int jt = jt_start; jt <= jt_end; ++jt) {
        const int j0 = jt << 6;
        const int buf = jt & 1;
        #pragma unroll
        for (int kk = 0; kk < 4; ++kk) {
            *(short8*)&Ks[buf][kkey[kk]*136 + kc16*8] = kreg[kk];
            *(short8*)&Vs[buf][vd[kk]*72 + vc8*8]     = vreg[kk];
        }
        __syncthreads();
        if (jt < jt_end) {
            const int j0n = j0 + 64;
            #pragma unroll
            for (int kk = 0; kk < 4; ++kk) {
                kreg[kk] = *(const short8*)(kb + (size_t)(j0n+kkey[kk])*EMB + h*HD + kc16*8);
                vreg[kk] = *(const short8*)(vt + (size_t)(h*HD + vd[kk])*T_SEQ + j0n + vc8*8);
            }
        }

        float4v s[4];
        __builtin_amdgcn_s_setprio(1);
        #pragma unroll
        for (int nt = 0; nt < 4; ++nt) {
            s[nt] = (float4v){0.f,0.f,0.f,0.f};
            #pragma unroll
            for (int ks = 0; ks < 4; ++ks) {
                short8 kf = *(const short8*)&Ks[buf][(nt*16 + cl)*136 + ks*32 + q*8];
                s[nt] = __builtin_amdgcn_mfma_f32_16x16x32_bf16(kf, qa[ks], s[nt], 0, 0, 0);  // SWAPPED
            }
        }
        __builtin_amdgcn_s_setprio(0);
        const bool needmask = (j0 + 63 > i0) || (j0 < i0 + 64 - W);
        const int irow = i0 + m0 + cl;
        #pragma unroll
        for (int nt = 0; nt < 4; ++nt) {
            #pragma unroll
            for (int r = 0; r < 4; ++r) {
                float sv = s[nt][r] * scale;
                if (needmask) {
                    int j = j0 + nt*16 + q*4 + r;
                    if (j > irow || j <= irow - W) sv = -1e30f;
                }
                s[nt][r] = __expf(sv);
            }
        }
        #pragma unroll
        for (int nt = 0; nt < 4; ++nt)
            lsum += s[nt][0] + s[nt][1] + s[nt][2] + s[nt][3];

        unsigned p01[4], p23[4];
        #pragma unroll
        for (int nt = 0; nt < 4; ++nt) {
            p01[nt] = pk2(s[nt][0], s[nt][1]);
            p23[nt] = pk2(s[nt][2], s[nt][3]);
        }
        short8 pa[2];
        #pragma unroll
        for (int k2 = 0; k2 < 2; ++k2) {
            unsigned a0 = (unsigned)__shfl((int)p01[2*k2  ], src0);
            unsigned b0 = (unsigned)__shfl((int)p01[2*k2+1], src0);
            unsigned a1 = (unsigned)__shfl((int)p23[2*k2  ], src0);
            unsigned b1 = (unsigned)__shfl((int)p23[2*k2+1], src0);
            unsigned a2 = (unsigned)__shfl((int)p01[2*k2  ], src1);
            unsigned b2 = (unsigned)__shfl((int)p01[2*k2+1], src1);
            unsigned a3 = (unsigned)__shfl((int)p23[2*k2  ], src1);
            unsigned b3 = (unsigned)__shfl((int)p23[2*k2+1], src1);
            uint4v w;
            w[0] = hi ? b0 : a0;
            w[1] = hi ? b1 : a1;
            w[2] = hi ? b2 : a2;
            w[3] = hi ? b3 : a3;
            __builtin_memcpy(&pa[k2], &w, 16);
        }

        __builtin_amdgcn_s_setprio(1);
        #pragma unroll
        for (int n = 0; n < 8; ++n) {
            #pragma unroll
            for (int k2 = 0; k2 < 2; ++k2) {
                short8 vf = *(const short8*)&Vs[buf][(n*16 + cl)*72 + k2*32 + q*8];
                o[n] = __builtin_amdgcn_mfma_f32_16x16x32_bf16(pa[k2], vf, o[n], 0, 0, 0);
            }
        }
        __builtin_amdgcn_s_setprio(0);
    }
    lsum += __shfl_xor(lsum, 16);
    lsum += __shfl_xor(lsum, 32);
    #pragma unroll
    for (int r = 0; r < 4; ++r) {
        float inv = 1.f / __shfl(lsum, q*4 + r);
        int row = i0 + m0 + q*4 + r;
        #pragma unroll
        for (int n = 0; n < 8; ++n)
            yb[(size_t)row*EMB + h*HD + n*16 + cl] = f2bs(o[n][r] * inv);
    }
}

// ---------------------------------------------------------------------------
extern "C" void kernel_launch(void* const* d_in, const int* in_sizes, int n_in,
                              void* d_out, int out_size, void* d_ws, size_t ws_size,
                              hipStream_t stream)
{
    const float* x    = (const float*)d_in[0];
    const float* ve   = (const float*)d_in[1];
    const float* cosb = (const float*)d_in[2];
    const float* sinb = (const float*)d_in[3];
    const float* wq   = (const float*)d_in[4];
    const float* wk   = (const float*)d_in[5];
    const float* wv   = (const float*)d_in[6];
    const float* wg   = (const float*)d_in[7];
    const float* wp   = (const float*)d_in[8];
    const int*   wsz  = (const int*)d_in[9];
    float* out = (float*)d_out;

    const size_t SEG = (size_t)T_SEQ * EMB;        // 4M elements = 8 MB bf16
    short* xb  = (short*)d_ws;                     // read only by qkv
    short* wbT = xb + SEG;                         // wq|wk|wv|wp transposed
    short* qb  = wbT + SEG;
    short* kb  = qb + SEG;
    short* vt  = kb + SEG;                         // 40 MB total
    short* yb  = xb;                               // alias: xb dead after qkv

    convert_all<<<dim3(64, 16, 5), 256, 0, stream>>>(wq, wk, wv, wp, x, wbT, xb);
    qkv_gemm_mfma<<<dim3(12, 16), 512, 0, stream>>>(xb, wbT, cosb, sinb,
                                                    x, ve, wg, qb, kb, vt);
    attn_flash<<<dim3(NH, T_SEQ/64), 256, 0, stream>>>((bf16*)qb, (bf16*)kb, (bf16*)vt, (bf16*)yb, wsz);
    proj_gemm_mfma<<<dim3(16, 32), 256, 0, stream>>>(yb, wbT + (size_t)3*EMB*EMB, out);
}

// Round 12
// 204.798 us; speedup vs baseline: 1.0521x; 1.0521x over previous
//
#include <hip/hip_runtime.h>
#include <hip/hip_bf16.h>
#include <math.h>

#define T_SEQ 4096
#define EMB   1024
#define NH    8
#define HD    128
#define HALF  64

typedef __hip_bfloat16 bf16;
typedef __attribute__((ext_vector_type(8))) short short8;
typedef __attribute__((ext_vector_type(4))) short short4v;
typedef __attribute__((ext_vector_type(4))) float float4v;
typedef __attribute__((ext_vector_type(4))) unsigned int uint4v;

static __device__ __forceinline__ float b2f(bf16 v) { return __bfloat162float(v); }
static __device__ __forceinline__ bf16  f2b(float v) { return __float2bfloat16(v); }
static __device__ __forceinline__ short f2bs(float v) {
    bf16 h = __float2bfloat16(v); short s; __builtin_memcpy(&s, &h, 2); return s;
}
static __device__ __forceinline__ unsigned pk2(float a, float b) {
    return (unsigned)(unsigned short)f2bs(a) | ((unsigned)(unsigned short)f2bs(b) << 16);
}
// async global->LDS, 16B per lane; lds base must be wave-uniform
static __device__ __forceinline__ void gload16(const short* g, short* l) {
    __builtin_amdgcn_global_load_lds((__attribute__((address_space(1))) void*)g,
                                     (__attribute__((address_space(3))) void*)l, 16, 0, 0);
}

// ---------------------------------------------------------------------------
// Converters: z<4 -> weight transpose W[k][n] fp32 -> wbT[z][n][k] bf16;
// z==4 -> x fp32 -> bf16. The xb pre-pass is bandwidth compression: qkv
// reads the A panel 24x (once per n-block); bf16 halves that traffic
// (R8 fusion attempt: FETCH 55.6->86.9 MB, qkv +20us — reverted).
// ---------------------------------------------------------------------------
__global__ __launch_bounds__(256) void convert_all(
    const float* __restrict__ w0, const float* __restrict__ w1,
    const float* __restrict__ w2, const float* __restrict__ w3,
    const float* __restrict__ x,
    short* __restrict__ wbT, short* __restrict__ xb)
{
    const int tid = threadIdx.x;
    if (blockIdx.z == 4) {
        const int r0 = blockIdx.x * 64;
        const int c0 = blockIdx.y * 64;
        #pragma unroll
        for (int t = 0; t < 4; ++t) {
            int id = tid + t*256;
            int r = id >> 4, c4 = id & 15;
            float4 f = *(const float4*)(x + (size_t)(r0+r)*EMB + c0 + c4*4);
            short4v s = { f2bs(f.x), f2bs(f.y), f2bs(f.z), f2bs(f.w) };
            *(short4v*)(xb + (size_t)(r0+r)*EMB + c0 + c4*4) = s;
        }
        return;
    }
    if (blockIdx.x >= 16) return;
    const float* W = (blockIdx.z==0)?w0:(blockIdx.z==1)?w1:(blockIdx.z==2)?w2:w3;
    short* dst = wbT + (size_t)blockIdx.z * EMB * EMB;
    __shared__ float tile[64][65];
    const int k0 = blockIdx.x * 64;
    const int n0 = blockIdx.y * 64;
    #pragma unroll
    for (int t = 0; t < 4; ++t) {
        int id = tid + t*256;
        int r = id >> 4, c4 = id & 15;
        float4 f = *(const float4*)(W + (size_t)(k0+r)*EMB + n0 + c4*4);
        tile[r][c4*4+0]=f.x; tile[r][c4*4+1]=f.y; tile[r][c4*4+2]=f.z; tile[r][c4*4+3]=f.w;
    }
    __syncthreads();
    #pragma unroll
    for (int t = 0; t < 4; ++t) {
        int id = tid + t*256;
        int n = id >> 4, k4 = id & 15;
        short4v s;
        #pragma unroll
        for (int j = 0; j < 4; ++j) s[j] = f2bs(tile[k4*4+j][n]);
        *(short4v*)(dst + (size_t)(n0+n)*EMB + k0 + k4*4) = s;
    }
}

// ---------------------------------------------------------------------------
// MFMA GEMM, BK=64 (session-best: 49.5us, 502 TF). A in register dbuf from
// xb (bf16, L2-hot), B in 3-buffer LDS ring, depth-2 COUNTED vmcnt (T3+T4).
// vmcnt ledger (per iter: loadA x4 then stageB x4, in-order retire):
//   steady queue at wait = [B(kt)4, A(kt)4, B(kt+1)4] = 12 -> vmcnt(4).
// WAR on 3-ring: stage(kt+2) after barrier(kt) overwrites tile kt-1 whose
// reads completed before MFMA(kt-1) < barrier(kt) -> safe.
// LDS layout: row = 8 x 16B units, phys unit = logical ^ (row&7); inverse
// on the global source. Read: pu = ((ks*4+q) ^ (cl&7)) * 8.
// This is the verified 2-phase plateau (m233): further gains require a
// structure this problem's geometry can't support (8-phase 256² needs
// grid >> #CU; here 192 blocks = 75% coverage -> measured 60.3us, worse).
// Epilogues: z<2 -> register RoPE+RMS (q/k); z==2 -> +gate*ve, store
// directly transposed into vt[h][d][t].
// ---------------------------------------------------------------------------
__global__ __launch_bounds__(256, 3) void qkv_gemm_mfma(
    const short* __restrict__ xb, const short* __restrict__ wbT,
    const float* __restrict__ cosb, const float* __restrict__ sinb,
    const float* __restrict__ x, const float* __restrict__ ve,
    const float* __restrict__ wg,
    short* __restrict__ qb, short* __restrict__ kb, short* __restrict__ vt)
{
    __shared__ short Bs[3][128*64];    // 3 x 16 KB = 48 KB
    __shared__ float gbuf[128];
    const int n0g = blockIdx.x * 128;
    const int m0  = blockIdx.y * 128;
    const int z   = n0g >> 10;
    const int ncol0 = n0g & 1023;
    const int h = ncol0 >> 7;
    const int tid = threadIdx.x;
    const int wv = tid >> 6, lane = tid & 63;
    const int cl = lane & 15, q = lane >> 4;
    const int lrow8 = lane >> 3;
    const int lunit = (lane & 7) ^ (lrow8 & 7);

    if (z == 2 && tid < 128) {      // per-row gate for the v epilogue
        float s = 0.f;
        const float4* xr = (const float4*)(x + (size_t)(m0 + tid)*EMB);
        #pragma unroll
        for (int c4 = 0; c4 < 8; ++c4) {
            float4 f = xr[c4];
            s += f.x * wg[(c4*4+0)*NH + h] + f.y * wg[(c4*4+1)*NH + h]
               + f.z * wg[(c4*4+2)*NH + h] + f.w * wg[(c4*4+3)*NH + h];
        }
        gbuf[tid] = 2.f / (1.f + __expf(-s));
    }
    __syncthreads();    // publish gbuf; drains gate loads -> vmcnt==0 baseline
    __builtin_amdgcn_sched_barrier(0);

    const short* arow0 = xb + (size_t)(m0 + wv*32 +      cl)*EMB + q*8;
    const short* arow1 = xb + (size_t)(m0 + wv*32 + 16 + cl)*EMB + q*8;

    short8 afr[2][4];   // [slot][mi*2+ks]
    auto loadA = [&](int slot, int k0) {
        afr[slot][0] = *(const short8*)(arow0 + k0);
        afr[slot][1] = *(const short8*)(arow0 + k0 + 32);
        afr[slot][2] = *(const short8*)(arow1 + k0);
        afr[slot][3] = *(const short8*)(arow1 + k0 + 32);
    };
    auto stageB = [&](int b, int k0) {
        #pragma unroll
        for (int t = 0; t < 4; ++t) {
            int chunk = wv*4 + t;                 // 16 chunks x 8 rows
            int row = chunk*8 + lrow8;
            gload16(wbT + (size_t)(n0g + row)*EMB + k0 + lunit*8, &Bs[b][chunk*512]);
        }
    };

    float4v acc[2][8];
    #pragma unroll
    for (int mi=0;mi<2;++mi)
        #pragma unroll
        for (int ni=0;ni<8;++ni) acc[mi][ni]=(float4v){0.f,0.f,0.f,0.f};

    loadA(0, 0);       // A(0): 4 loads
    stageB(0, 0);      // B(0): 4 loads
    stageB(1, 64);     // B(1): 4 loads   -> queue [A0 B0 B1] = 12

    #pragma unroll
    for (int kt = 0; kt < 16; ++kt) {
        const int cur = kt % 3;
        if (kt < 15) {
            asm volatile("s_waitcnt vmcnt(4)" ::: "memory");   // B(kt),A(kt) landed
        } else {
            asm volatile("s_waitcnt vmcnt(0)" ::: "memory");
        }
        __builtin_amdgcn_s_barrier();             // everyone's B tile kt landed
        __builtin_amdgcn_sched_barrier(0);        // pin: nothing crosses the barrier
        if (kt < 15) loadA((kt + 1) & 1, (kt + 1) * 64);
        if (kt < 14) stageB((kt + 2) % 3, (kt + 2) * 64);  // after barrier: 3-ring WAR safe
        #pragma unroll
        for (int ks = 0; ks < 2; ++ks) {
            const int pu = ((ks*4 + q) ^ (cl & 7)) * 8;    // swizzled unit offset
            short8 bfr[8];
            #pragma unroll
            for (int ni=0;ni<8;++ni)
                bfr[ni] = *(const short8*)&Bs[cur][(ni*16+cl)*64 + pu];
            #pragma unroll
            for (int mi=0;mi<2;++mi)
                #pragma unroll
                for (int ni=0;ni<8;++ni)
                    acc[mi][ni] = __builtin_amdgcn_mfma_f32_16x16x32_bf16(afr[kt & 1][mi*2+ks], bfr[ni], acc[mi][ni], 0, 0, 0);
        }
    }

    if (z == 2) {   // v: add gate*ve, store transposed vt[h][d][t]
        #pragma unroll
        for (int mi=0;mi<2;++mi) {
            const int t0r = m0 + wv*32 + mi*16 + q*4;
            #pragma unroll
            for (int ni=0;ni<8;++ni) {
                const int d = ni*16 + cl;
                short4v ov;
                #pragma unroll
                for (int r=0;r<4;++r) {
                    const int t = t0r + r;
                    float v = acc[mi][ni][r]
                            + gbuf[t - m0] * ve[(size_t)t*EMB + h*HD + d];
                    ov[r] = f2bs(v);
                }
                *(short4v*)(vt + (size_t)(h*HD + d)*T_SEQ + t0r) = ov;
            }
        }
        return;
    }
    // q/k: rope + rms in registers (pair (d,d+64) = (ni, ni+4))
    short* dstb = (z == 0) ? qb : kb;
    #pragma unroll
    for (int mi=0;mi<2;++mi) {
        #pragma unroll
        for (int r=0;r<4;++r) {
            const int t = m0 + wv*32 + mi*16 + q*4 + r;
            float y1[4], y2[4];
            float ss = 0.f;
            #pragma unroll
            for (int ni=0;ni<4;++ni) {
                const int d = ni*16 + cl;
                float c = cosb[(size_t)t*HALF + d];
                float s = sinb[(size_t)t*HALF + d];
                float x1 = acc[mi][ni][r];
                float x2 = acc[mi][ni+4][r];
                y1[ni] = x1*c + x2*s;
                y2[ni] = x2*c - x1*s;
                ss += y1[ni]*y1[ni] + y2[ni]*y2[ni];
            }
            ss += __shfl_xor(ss, 1);
            ss += __shfl_xor(ss, 2);
            ss += __shfl_xor(ss, 4);
            ss += __shfl_xor(ss, 8);
            const float rr = rsqrtf(ss * (1.0f/HD) + 1e-6f);
            short* dst = dstb + (size_t)t*EMB + h*HD;
            #pragma unroll
            for (int ni=0;ni<4;++ni) {
                dst[ni*16 + cl]        = f2bs(y1[ni]*rr);
                dst[ni*16 + cl + HALF] = f2bs(y2[ni]*rr);
            }
        }
    }
}

// ---------------------------------------------------------------------------
// MFMA GEMM: out[4096,1024] fp32 = yb(bf16) @ wpT^T. 128x64 tile -> 512
// blocks = 2/CU. ROUND-0 VERBATIM (2-barrier form; three pipeline variants
// never beat it on this short K-loop — m141 pattern).
// ---------------------------------------------------------------------------
__global__ __launch_bounds__(256) void proj_gemm_mfma(
    const short* __restrict__ yb, const short* __restrict__ wpT,
    float* __restrict__ out)
{
    __shared__ short As[128*32];    // 8 KB
    __shared__ short Bs[64*32];     // 4 KB
    const int n0 = blockIdx.x * 64;
    const int m0 = blockIdx.y * 128;
    const int tid = threadIdx.x;
    const int wv = tid >> 6, lane = tid & 63;
    const int cl = lane & 15, q = lane >> 4;
    const int lrow = lane >> 2;
    const int lcol = (lane & 3) * 8;
    float4v acc[2][4];
    #pragma unroll
    for (int mi=0;mi<2;++mi)
        #pragma unroll
        for (int ni=0;ni<4;++ni) acc[mi][ni]=(float4v){0.f,0.f,0.f,0.f};

    for (int k0 = 0; k0 < EMB; k0 += 32) {
        __syncthreads();
        #pragma unroll
        for (int t = 0; t < 2; ++t) {
            int chunk = wv*2 + t;
            gload16(yb + (size_t)(m0 + chunk*16 + lrow)*EMB + k0 + lcol, &As[chunk*512]);
        }
        gload16(wpT + (size_t)(n0 + wv*16 + lrow)*EMB + k0 + lcol, &Bs[wv*512]);
        __syncthreads();
        short8 af[2], bfr[4];
        #pragma unroll
        for (int mi=0;mi<2;++mi) af[mi]  = *(const short8*)&As[(wv*32+mi*16+cl)*32 + q*8];
        #pragma unroll
        for (int ni=0;ni<4;++ni) bfr[ni] = *(const short8*)&Bs[(ni*16+cl)*32 + q*8];
        #pragma unroll
        for (int mi=0;mi<2;++mi)
            #pragma unroll
            for (int ni=0;ni<4;++ni)
                acc[mi][ni] = __builtin_amdgcn_mfma_f32_16x16x32_bf16(af[mi], bfr[ni], acc[mi][ni], 0, 0, 0);
    }
    #pragma unroll
    for (int mi=0;mi<2;++mi)
        #pragma unroll
        for (int ni=0;ni<4;++ni)
            #pragma unroll
            for (int r=0;r<4;++r)
                out[(size_t)(m0+wv*32+mi*16+q*4+r)*EMB + n0 + ni*16+cl] = acc[mi][ni][r];
}

// ---------------------------------------------------------------------------
// Flash attention: swapped QK^T (s = mfma(kf,qa) -> lane holds S[key][query],
// row-sum lane-local), in-register P->bf16 A-fragments via pack + shfl
// (no Ps LDS round-trip), double-buffered K/V LDS with ONE barrier per
// key-tile, s_setprio around both MFMA clusters (m191).
// ---------------------------------------------------------------------------
__global__ __launch_bounds__(256) void attn_flash(
    const bf16* __restrict__ qbh, const bf16* __restrict__ kbh,
    const bf16* __restrict__ vth, bf16* __restrict__ ybh,
    const int* __restrict__ wptr)
{
    const short* qb = (const short*)qbh;
    const short* kb = (const short*)kbh;
    const short* vt = (const short*)vth;
    short* yb = (short*)ybh;

    __shared__ short Ks[2][64*136];
    __shared__ short Vs[2][128*72];

    int W = *wptr; W = min(max(W, 1), 1024);
    const int h  = blockIdx.x;
    const int i0 = blockIdx.y * 64;
    const int tid  = threadIdx.x;
    const int wv   = tid >> 6;
    const int lane = tid & 63;
    const int cl   = lane & 15;
    const int q    = lane >> 4;
    const int m0   = wv * 16;
    const float scale = 0.08838834764831845f;

    short8 qa[4];
    {
        const short* qbase = qb + (size_t)(i0 + m0 + cl) * EMB + h*HD + q*8;
        #pragma unroll
        for (int ks = 0; ks < 4; ++ks)
            qa[ks] = *(const short8*)(qbase + ks*32);
    }

    float4v o[8];
    #pragma unroll
    for (int n = 0; n < 8; ++n) o[n] = (float4v){0.f,0.f,0.f,0.f};
    float lsum = 0.f;

    const int lo_key  = i0 - W + 1;
    const int jt_start = lo_key > 0 ? (lo_key >> 6) : 0;
    const int jt_end   = i0 >> 6;

    const int kkey[4] = { (tid+0)>>4, (tid+256)>>4, (tid+512)>>4, (tid+768)>>4 };
    const int kc16 = tid & 15;
    const int vd[4] = { (tid+0)>>3, (tid+256)>>3, (tid+512)>>3, (tid+768)>>3 };
    const int vc8 = tid & 7;

    const int src0 = cl + ((lane >> 4) & 1) * 32;
    const int src1 = src0 + 16;
    const bool hi  = (lane & 32) != 0;

    short8 kreg[4], vreg[4];
    {
        const int j0 = jt_start << 6;
        #pragma unroll
        for (int kk = 0; kk < 4; ++kk) {
            kreg[kk] = *(const short8*)(kb + (size_t)(j0+kkey[kk])*EMB + h*HD + kc16*8);
            vreg[kk] = *(const short8*)(vt + (size_t)(h*HD + vd[kk])*T_SEQ + j0 + vc8*8);
        }
    }

    for (int jt = jt_start; jt <= jt_end; ++jt) {
        const int j0 = jt << 6;
        const int buf = jt & 1;
        #pragma unroll
        for (int kk = 0; kk < 4; ++kk) {
            *(short8*)&Ks[buf][kkey[kk]*136 + kc16*8] = kreg[kk];
            *(short8*)&Vs[buf][vd[kk]*72 + vc8*8]     = vreg[kk];
        }
        __syncthreads();
        if (jt < jt_end) {
            const int j0n = j0 + 64;
            #pragma unroll
            for (int kk = 0; kk < 4; ++kk) {
                kreg[kk] = *(const short8*)(kb + (size_t)(j0n+kkey[kk])*EMB + h*HD + kc16*8);
                vreg[kk] = *(const short8*)(vt + (size_t)(h*HD + vd[kk])*T_SEQ + j0n + vc8*8);
            }
        }

        float4v s[4];
        __builtin_amdgcn_s_setprio(1);
        #pragma unroll
        for (int nt = 0; nt < 4; ++nt) {
            s[nt] = (float4v){0.f,0.f,0.f,0.f};
            #pragma unroll
            for (int ks = 0; ks < 4; ++ks) {
                short8 kf = *(const short8*)&Ks[buf][(nt*16 + cl)*136 + ks*32 + q*8];
                s[nt] = __builtin_amdgcn_mfma_f32_16x16x32_bf16(kf, qa[ks], s[nt], 0, 0, 0);  // SWAPPED
            }
        }
        __builtin_amdgcn_s_setprio(0);
        const bool needmask = (j0 + 63 > i0) || (j0 < i0 + 64 - W);
        const int irow = i0 + m0 + cl;
        #pragma unroll
        for (int nt = 0; nt < 4; ++nt) {
            #pragma unroll
            for (int r = 0; r < 4; ++r) {
                float sv = s[nt][r] * scale;
                if (needmask) {
                    int j = j0 + nt*16 + q*4 + r;
                    if (j > irow || j <= irow - W) sv = -1e30f;
                }
                s[nt][r] = __expf(sv);
            }
        }
        #pragma unroll
        for (int nt = 0; nt < 4; ++nt)
            lsum += s[nt][0] + s[nt][1] + s[nt][2] + s[nt][3];

        unsigned p01[4], p23[4];
        #pragma unroll
        for (int nt = 0; nt < 4; ++nt) {
            p01[nt] = pk2(s[nt][0], s[nt][1]);
            p23[nt] = pk2(s[nt][2], s[nt][3]);
        }
        short8 pa[2];
        #pragma unroll
        for (int k2 = 0; k2 < 2; ++k2) {
            unsigned a0 = (unsigned)__shfl((int)p01[2*k2  ], src0);
            unsigned b0 = (unsigned)__shfl((int)p01[2*k2+1], src0);
            unsigned a1 = (unsigned)__shfl((int)p23[2*k2  ], src0);
            unsigned b1 = (unsigned)__shfl((int)p23[2*k2+1], src0);
            unsigned a2 = (unsigned)__shfl((int)p01[2*k2  ], src1);
            unsigned b2 = (unsigned)__shfl((int)p01[2*k2+1], src1);
            unsigned a3 = (unsigned)__shfl((int)p23[2*k2  ], src1);
            unsigned b3 = (unsigned)__shfl((int)p23[2*k2+1], src1);
            uint4v w;
            w[0] = hi ? b0 : a0;
            w[1] = hi ? b1 : a1;
            w[2] = hi ? b2 : a2;
            w[3] = hi ? b3 : a3;
            __builtin_memcpy(&pa[k2], &w, 16);
        }

        __builtin_amdgcn_s_setprio(1);
        #pragma unroll
        for (int n = 0; n < 8; ++n) {
            #pragma unroll
            for (int k2 = 0; k2 < 2; ++k2) {
                short8 vf = *(const short8*)&Vs[buf][(n*16 + cl)*72 + k2*32 + q*8];
                o[n] = __builtin_amdgcn_mfma_f32_16x16x32_bf16(pa[k2], vf, o[n], 0, 0, 0);
            }
        }
        __builtin_amdgcn_s_setprio(0);
    }
    lsum += __shfl_xor(lsum, 16);
    lsum += __shfl_xor(lsum, 32);
    #pragma unroll
    for (int r = 0; r < 4; ++r) {
        float inv = 1.f / __shfl(lsum, q*4 + r);
        int row = i0 + m0 + q*4 + r;
        #pragma unroll
        for (int n = 0; n < 8; ++n)
            yb[(size_t)row*EMB + h*HD + n*16 + cl] = f2bs(o[n][r] * inv);
    }
}

// ---------------------------------------------------------------------------
extern "C" void kernel_launch(void* const* d_in, const int* in_sizes, int n_in,
                              void* d_out, int out_size, void* d_ws, size_t ws_size,
                              hipStream_t stream)
{
    const float* x    = (const float*)d_in[0];
    const float* ve   = (const float*)d_in[1];
    const float* cosb = (const float*)d_in[2];
    const float* sinb = (const float*)d_in[3];
    const float* wq   = (const float*)d_in[4];
    const float* wk   = (const float*)d_in[5];
    const float* wv   = (const float*)d_in[6];
    const float* wg   = (const float*)d_in[7];
    const float* wp   = (const float*)d_in[8];
    const int*   wsz  = (const int*)d_in[9];
    float* out = (float*)d_out;

    const size_t SEG = (size_t)T_SEQ * EMB;        // 4M elements = 8 MB bf16
    short* xb  = (short*)d_ws;                     // read only by qkv
    short* wbT = xb + SEG;                         // wq|wk|wv|wp transposed
    short* qb  = wbT + SEG;
    short* kb  = qb + SEG;
    short* vt  = kb + SEG;                         // 40 MB total
    short* yb  = xb;                               // alias: xb dead after qkv

    convert_all<<<dim3(64, 16, 5), 256, 0, stream>>>(wq, wk, wv, wp, x, wbT, xb);
    qkv_gemm_mfma<<<dim3(24, 32), 256, 0, stream>>>(xb, wbT, cosb, sinb,
                                                    x, ve, wg, qb, kb, vt);
    attn_flash<<<dim3(NH, T_SEQ/64), 256, 0, stream>>>((bf16*)qb, (bf16*)kb, (bf16*)vt, (bf16*)yb, wsz);
    proj_gemm_mfma<<<dim3(16, 32), 256, 0, stream>>>(yb, wbT + (size_t)3*EMB*EMB, out);
}

// Round 13
// 201.676 us; speedup vs baseline: 1.0684x; 1.0155x over previous
//
#include <hip/hip_runtime.h>
#include <hip/hip_bf16.h>
#include <math.h>

#define T_SEQ 4096
#define EMB   1024
#define NH    8
#define HD    128
#define HALF  64

typedef __hip_bfloat16 bf16;
typedef __attribute__((ext_vector_type(8))) short short8;
typedef __attribute__((ext_vector_type(4))) short short4v;
typedef __attribute__((ext_vector_type(4))) float float4v;
typedef __attribute__((ext_vector_type(4))) unsigned int uint4v;

static __device__ __forceinline__ float b2f(bf16 v) { return __bfloat162float(v); }
static __device__ __forceinline__ bf16  f2b(float v) { return __float2bfloat16(v); }
static __device__ __forceinline__ short f2bs(float v) {
    bf16 h = __float2bfloat16(v); short s; __builtin_memcpy(&s, &h, 2); return s;
}
static __device__ __forceinline__ unsigned pk2(float a, float b) {
    return (unsigned)(unsigned short)f2bs(a) | ((unsigned)(unsigned short)f2bs(b) << 16);
}
// async global->LDS, 16B per lane; lds base must be wave-uniform
static __device__ __forceinline__ void gload16(const short* g, short* l) {
    __builtin_amdgcn_global_load_lds((__attribute__((address_space(1))) void*)g,
                                     (__attribute__((address_space(3))) void*)l, 16, 0, 0);
}

// ---------------------------------------------------------------------------
// Converters: z<4 -> weight transpose W[k][n] fp32 -> wbT[z][n][k] bf16;
// z==4 -> x fp32 -> bf16. The xb pre-pass is bandwidth compression: qkv
// reads the A panel 24x; bf16 halves that traffic (R8 fusion attempt:
// FETCH 55.6->86.9 MB, qkv +20us — reverted).
// ---------------------------------------------------------------------------
__global__ __launch_bounds__(256) void convert_all(
    const float* __restrict__ w0, const float* __restrict__ w1,
    const float* __restrict__ w2, const float* __restrict__ w3,
    const float* __restrict__ x,
    short* __restrict__ wbT, short* __restrict__ xb)
{
    const int tid = threadIdx.x;
    if (blockIdx.z == 4) {
        const int r0 = blockIdx.x * 64;
        const int c0 = blockIdx.y * 64;
        #pragma unroll
        for (int t = 0; t < 4; ++t) {
            int id = tid + t*256;
            int r = id >> 4, c4 = id & 15;
            float4 f = *(const float4*)(x + (size_t)(r0+r)*EMB + c0 + c4*4);
            short4v s = { f2bs(f.x), f2bs(f.y), f2bs(f.z), f2bs(f.w) };
            *(short4v*)(xb + (size_t)(r0+r)*EMB + c0 + c4*4) = s;
        }
        return;
    }
    if (blockIdx.x >= 16) return;
    const float* W = (blockIdx.z==0)?w0:(blockIdx.z==1)?w1:(blockIdx.z==2)?w2:w3;
    short* dst = wbT + (size_t)blockIdx.z * EMB * EMB;
    __shared__ float tile[64][65];
    const int k0 = blockIdx.x * 64;
    const int n0 = blockIdx.y * 64;
    #pragma unroll
    for (int t = 0; t < 4; ++t) {
        int id = tid + t*256;
        int r = id >> 4, c4 = id & 15;
        float4 f = *(const float4*)(W + (size_t)(k0+r)*EMB + n0 + c4*4);
        tile[r][c4*4+0]=f.x; tile[r][c4*4+1]=f.y; tile[r][c4*4+2]=f.z; tile[r][c4*4+3]=f.w;
    }
    __syncthreads();
    #pragma unroll
    for (int t = 0; t < 4; ++t) {
        int id = tid + t*256;
        int n = id >> 4, k4 = id & 15;
        short4v s;
        #pragma unroll
        for (int j = 0; j < 4; ++j) s[j] = f2bs(tile[k4*4+j][n]);
        *(short4v*)(dst + (size_t)(n0+n)*EMB + k0 + k4*4) = s;
    }
}

// ---------------------------------------------------------------------------
// MFMA GEMM, BK=64 (session-best: ~50us, 502 TF). A in register dbuf from
// xb (bf16, L2-hot), B in 3-buffer LDS ring, depth-2 COUNTED vmcnt (T3+T4).
// vmcnt ledger (per iter: loadA x4 then stageB x4, in-order retire):
//   steady queue at wait = [B(kt)4, A(kt)4, B(kt+1)4] = 12 -> vmcnt(4).
// WAR on 3-ring: stage(kt+2) after barrier(kt) overwrites tile kt-1 whose
// reads completed before MFMA(kt-1) < barrier(kt) -> safe.
// LDS layout: row = 8 x 16B units, phys unit = logical ^ (row&7); inverse
// on the global source. Read: pu = ((ks*4+q) ^ (cl&7)) * 8.
// Verified 2-phase plateau (m233); 8-phase 256² at this grid (192 blocks =
// 75% CU coverage) measured WORSE (60.3us, R11) — branch closed.
// Epilogues: z<2 -> register RoPE+RMS (q/k); z==2 -> +gate*ve, store
// directly transposed into vt[h][d][t].
// ---------------------------------------------------------------------------
__global__ __launch_bounds__(256, 3) void qkv_gemm_mfma(
    const short* __restrict__ xb, const short* __restrict__ wbT,
    const float* __restrict__ cosb, const float* __restrict__ sinb,
    const float* __restrict__ x, const float* __restrict__ ve,
    const float* __restrict__ wg,
    short* __restrict__ qb, short* __restrict__ kb, short* __restrict__ vt)
{
    __shared__ short Bs[3][128*64];    // 3 x 16 KB = 48 KB
    __shared__ float gbuf[128];
    const int n0g = blockIdx.x * 128;
    const int m0  = blockIdx.y * 128;
    const int z   = n0g >> 10;
    const int ncol0 = n0g & 1023;
    const int h = ncol0 >> 7;
    const int tid = threadIdx.x;
    const int wv = tid >> 6, lane = tid & 63;
    const int cl = lane & 15, q = lane >> 4;
    const int lrow8 = lane >> 3;
    const int lunit = (lane & 7) ^ (lrow8 & 7);

    if (z == 2 && tid < 128) {      // per-row gate for the v epilogue
        float s = 0.f;
        const float4* xr = (const float4*)(x + (size_t)(m0 + tid)*EMB);
        #pragma unroll
        for (int c4 = 0; c4 < 8; ++c4) {
            float4 f = xr[c4];
            s += f.x * wg[(c4*4+0)*NH + h] + f.y * wg[(c4*4+1)*NH + h]
               + f.z * wg[(c4*4+2)*NH + h] + f.w * wg[(c4*4+3)*NH + h];
        }
        gbuf[tid] = 2.f / (1.f + __expf(-s));
    }
    __syncthreads();    // publish gbuf; drains gate loads -> vmcnt==0 baseline
    __builtin_amdgcn_sched_barrier(0);

    const short* arow0 = xb + (size_t)(m0 + wv*32 +      cl)*EMB + q*8;
    const short* arow1 = xb + (size_t)(m0 + wv*32 + 16 + cl)*EMB + q*8;

    short8 afr[2][4];   // [slot][mi*2+ks]
    auto loadA = [&](int slot, int k0) {
        afr[slot][0] = *(const short8*)(arow0 + k0);
        afr[slot][1] = *(const short8*)(arow0 + k0 + 32);
        afr[slot][2] = *(const short8*)(arow1 + k0);
        afr[slot][3] = *(const short8*)(arow1 + k0 + 32);
    };
    auto stageB = [&](int b, int k0) {
        #pragma unroll
        for (int t = 0; t < 4; ++t) {
            int chunk = wv*4 + t;                 // 16 chunks x 8 rows
            int row = chunk*8 + lrow8;
            gload16(wbT + (size_t)(n0g + row)*EMB + k0 + lunit*8, &Bs[b][chunk*512]);
        }
    };

    float4v acc[2][8];
    #pragma unroll
    for (int mi=0;mi<2;++mi)
        #pragma unroll
        for (int ni=0;ni<8;++ni) acc[mi][ni]=(float4v){0.f,0.f,0.f,0.f};

    loadA(0, 0);       // A(0): 4 loads
    stageB(0, 0);      // B(0): 4 loads
    stageB(1, 64);     // B(1): 4 loads   -> queue [A0 B0 B1] = 12

    #pragma unroll
    for (int kt = 0; kt < 16; ++kt) {
        const int cur = kt % 3;
        if (kt < 15) {
            asm volatile("s_waitcnt vmcnt(4)" ::: "memory");   // B(kt),A(kt) landed
        } else {
            asm volatile("s_waitcnt vmcnt(0)" ::: "memory");
        }
        __builtin_amdgcn_s_barrier();             // everyone's B tile kt landed
        __builtin_amdgcn_sched_barrier(0);        // pin: nothing crosses the barrier
        if (kt < 15) loadA((kt + 1) & 1, (kt + 1) * 64);
        if (kt < 14) stageB((kt + 2) % 3, (kt + 2) * 64);  // after barrier: 3-ring WAR safe
        #pragma unroll
        for (int ks = 0; ks < 2; ++ks) {
            const int pu = ((ks*4 + q) ^ (cl & 7)) * 8;    // swizzled unit offset
            short8 bfr[8];
            #pragma unroll
            for (int ni=0;ni<8;++ni)
                bfr[ni] = *(const short8*)&Bs[cur][(ni*16+cl)*64 + pu];
            #pragma unroll
            for (int mi=0;mi<2;++mi)
                #pragma unroll
                for (int ni=0;ni<8;++ni)
                    acc[mi][ni] = __builtin_amdgcn_mfma_f32_16x16x32_bf16(afr[kt & 1][mi*2+ks], bfr[ni], acc[mi][ni], 0, 0, 0);
        }
    }

    if (z == 2) {   // v: add gate*ve, store transposed vt[h][d][t]
        #pragma unroll
        for (int mi=0;mi<2;++mi) {
            const int t0r = m0 + wv*32 + mi*16 + q*4;
            #pragma unroll
            for (int ni=0;ni<8;++ni) {
                const int d = ni*16 + cl;
                short4v ov;
                #pragma unroll
                for (int r=0;r<4;++r) {
                    const int t = t0r + r;
                    float v = acc[mi][ni][r]
                            + gbuf[t - m0] * ve[(size_t)t*EMB + h*HD + d];
                    ov[r] = f2bs(v);
                }
                *(short4v*)(vt + (size_t)(h*HD + d)*T_SEQ + t0r) = ov;
            }
        }
        return;
    }
    // q/k: rope + rms in registers (pair (d,d+64) = (ni, ni+4))
    short* dstb = (z == 0) ? qb : kb;
    #pragma unroll
    for (int mi=0;mi<2;++mi) {
        #pragma unroll
        for (int r=0;r<4;++r) {
            const int t = m0 + wv*32 + mi*16 + q*4 + r;
            float y1[4], y2[4];
            float ss = 0.f;
            #pragma unroll
            for (int ni=0;ni<4;++ni) {
                const int d = ni*16 + cl;
                float c = cosb[(size_t)t*HALF + d];
                float s = sinb[(size_t)t*HALF + d];
                float x1 = acc[mi][ni][r];
                float x2 = acc[mi][ni+4][r];
                y1[ni] = x1*c + x2*s;
                y2[ni] = x2*c - x1*s;
                ss += y1[ni]*y1[ni] + y2[ni]*y2[ni];
            }
            ss += __shfl_xor(ss, 1);
            ss += __shfl_xor(ss, 2);
            ss += __shfl_xor(ss, 4);
            ss += __shfl_xor(ss, 8);
            const float rr = rsqrtf(ss * (1.0f/HD) + 1e-6f);
            short* dst = dstb + (size_t)t*EMB + h*HD;
            #pragma unroll
            for (int ni=0;ni<4;++ni) {
                dst[ni*16 + cl]        = f2bs(y1[ni]*rr);
                dst[ni*16 + cl + HALF] = f2bs(y2[ni]*rr);
            }
        }
    }
}

// ---------------------------------------------------------------------------
// MFMA GEMM: out[4096,1024] fp32 = yb(bf16) @ wpT^T. 128x64 tile -> 512
// blocks = 2/CU. ROUND-0 VERBATIM (2-barrier form; three pipeline variants
// never beat it on this short K-loop — m141 pattern).
// ---------------------------------------------------------------------------
__global__ __launch_bounds__(256) void proj_gemm_mfma(
    const short* __restrict__ yb, const short* __restrict__ wpT,
    float* __restrict__ out)
{
    __shared__ short As[128*32];    // 8 KB
    __shared__ short Bs[64*32];     // 4 KB
    const int n0 = blockIdx.x * 64;
    const int m0 = blockIdx.y * 128;
    const int tid = threadIdx.x;
    const int wv = tid >> 6, lane = tid & 63;
    const int cl = lane & 15, q = lane >> 4;
    const int lrow = lane >> 2;
    const int lcol = (lane & 3) * 8;
    float4v acc[2][4];
    #pragma unroll
    for (int mi=0;mi<2;++mi)
        #pragma unroll
        for (int ni=0;ni<4;++ni) acc[mi][ni]=(float4v){0.f,0.f,0.f,0.f};

    for (int k0 = 0; k0 < EMB; k0 += 32) {
        __syncthreads();
        #pragma unroll
        for (int t = 0; t < 2; ++t) {
            int chunk = wv*2 + t;
            gload16(yb + (size_t)(m0 + chunk*16 + lrow)*EMB + k0 + lcol, &As[chunk*512]);
        }
        gload16(wpT + (size_t)(n0 + wv*16 + lrow)*EMB + k0 + lcol, &Bs[wv*512]);
        __syncthreads();
        short8 af[2], bfr[4];
        #pragma unroll
        for (int mi=0;mi<2;++mi) af[mi]  = *(const short8*)&As[(wv*32+mi*16+cl)*32 + q*8];
        #pragma unroll
        for (int ni=0;ni<4;++ni) bfr[ni] = *(const short8*)&Bs[(ni*16+cl)*32 + q*8];
        #pragma unroll
        for (int mi=0;mi<2;++mi)
            #pragma unroll
            for (int ni=0;ni<4;++ni)
                acc[mi][ni] = __builtin_amdgcn_mfma_f32_16x16x32_bf16(af[mi], bfr[ni], acc[mi][ni], 0, 0, 0);
    }
    #pragma unroll
    for (int mi=0;mi<2;++mi)
        #pragma unroll
        for (int ni=0;ni<4;++ni)
            #pragma unroll
            for (int r=0;r<4;++r)
                out[(size_t)(m0+wv*32+mi*16+q*4+r)*EMB + n0 + ni*16+cl] = acc[mi][ni][r];
}

// ---------------------------------------------------------------------------
// Flash attention — R8 attn VERBATIM (session-best non-qkv = 148.3us):
// SINGLE-buffered K/V LDS (35.8 KB -> 4 blocks/CU = 16 waves/CU, double the
// dbuf variant's TLP; attn is latency-bound on the QK^T->softmax->PV chain,
// so resident waves, not barrier count, are the binding resource — R9's
// dbuf halved occupancy for ~nil barrier gain and cost ~5us).
// Swapped QK^T: s = mfma(kf,qa) -> lane holds S[key][query], row-sum
// lane-local; P->bf16 A-fragments in-register via pack + shfl (no Ps LDS
// round-trip). s_setprio around both MFMA clusters (m191).
// ---------------------------------------------------------------------------
__global__ __launch_bounds__(256) void attn_flash(
    const bf16* __restrict__ qbh, const bf16* __restrict__ kbh,
    const bf16* __restrict__ vth, bf16* __restrict__ ybh,
    const int* __restrict__ wptr)
{
    const short* qb = (const short*)qbh;
    const short* kb = (const short*)kbh;
    const short* vt = (const short*)vth;
    short* yb = (short*)ybh;

    __shared__ short Ks[64*136];
    __shared__ short Vs[128*72];

    int W = *wptr; W = min(max(W, 1), 1024);
    const int h  = blockIdx.x;
    const int i0 = blockIdx.y * 64;
    const int tid  = threadIdx.x;
    const int wv   = tid >> 6;
    const int lane = tid & 63;
    const int cl   = lane & 15;
    const int q    = lane >> 4;
    const int m0   = wv * 16;
    const float scale = 0.08838834764831845f;

    short8 qa[4];
    {
        const short* qbase = qb + (size_t)(i0 + m0 + cl) * EMB + h*HD + q*8;
        #pragma unroll
        for (int ks = 0; ks < 4; ++ks)
            qa[ks] = *(const short8*)(qbase + ks*32);
    }

    float4v o[8];
    #pragma unroll
    for (int n = 0; n < 8; ++n) o[n] = (float4v){0.f,0.f,0.f,0.f};
    float lsum = 0.f;

    const int lo_key  = i0 - W + 1;
    const int jt_start = lo_key > 0 ? (lo_key >> 6) : 0;
    const int jt_end   = i0 >> 6;

    const int kkey[4] = { (tid+0)>>4, (tid+256)>>4, (tid+512)>>4, (tid+768)>>4 };
    const int kc16 = tid & 15;
    const int vd[4] = { (tid+0)>>3, (tid+256)>>3, (tid+512)>>3, (tid+768)>>3 };
    const int vc8 = tid & 7;

    // pa-gather lane constants
    const int src0 = cl + ((lane >> 4) & 1) * 32;
    const int src1 = src0 + 16;
    const bool hi  = (lane & 32) != 0;   // q>>1

    short8 kreg[4], vreg[4];
    {
        const int j0 = jt_start << 6;
        #pragma unroll
        for (int kk = 0; kk < 4; ++kk) {
            kreg[kk] = *(const short8*)(kb + (size_t)(j0+kkey[kk])*EMB + h*HD + kc16*8);
            vreg[kk] = *(const short8*)(vt + (size_t)(h*HD + vd[kk])*T_SEQ + j0 + vc8*8);
        }
    }

    for (int jt = jt_start; jt <= jt_end; ++jt) {
        const int j0 = jt << 6;
        __syncthreads();
        #pragma unroll
        for (int kk = 0; kk < 4; ++kk) {
            *(short8*)&Ks[kkey[kk]*136 + kc16*8] = kreg[kk];
            *(short8*)&Vs[vd[kk]*72 + vc8*8]     = vreg[kk];
        }
        __syncthreads();
        if (jt < jt_end) {
            const int j0n = j0 + 64;
            #pragma unroll
            for (int kk = 0; kk < 4; ++kk) {
                kreg[kk] = *(const short8*)(kb + (size_t)(j0n+kkey[kk])*EMB + h*HD + kc16*8);
                vreg[kk] = *(const short8*)(vt + (size_t)(h*HD + vd[kk])*T_SEQ + j0n + vc8*8);
            }
        }

        float4v s[4];
        __builtin_amdgcn_s_setprio(1);
        #pragma unroll
        for (int nt = 0; nt < 4; ++nt) {
            s[nt] = (float4v){0.f,0.f,0.f,0.f};
            #pragma unroll
            for (int ks = 0; ks < 4; ++ks) {
                short8 kf = *(const short8*)&Ks[(nt*16 + cl)*136 + ks*32 + q*8];
                s[nt] = __builtin_amdgcn_mfma_f32_16x16x32_bf16(kf, qa[ks], s[nt], 0, 0, 0);  // SWAPPED
            }
        }
        __builtin_amdgcn_s_setprio(0);
        const bool needmask = (j0 + 63 > i0) || (j0 < i0 + 64 - W);
        const int irow = i0 + m0 + cl;     // this lane's query row
        #pragma unroll
        for (int nt = 0; nt < 4; ++nt) {
            #pragma unroll
            for (int r = 0; r < 4; ++r) {
                float sv = s[nt][r] * scale;
                if (needmask) {
                    int j = j0 + nt*16 + q*4 + r;
                    if (j > irow || j <= irow - W) sv = -1e30f;
                }
                s[nt][r] = __expf(sv);
            }
        }
        #pragma unroll
        for (int nt = 0; nt < 4; ++nt)
            lsum += s[nt][0] + s[nt][1] + s[nt][2] + s[nt][3];

        // pack P rows to bf16 pairs (keys r,r+1 adjacent in-lane)
        unsigned p01[4], p23[4];
        #pragma unroll
        for (int nt = 0; nt < 4; ++nt) {
            p01[nt] = pk2(s[nt][0], s[nt][1]);
            p23[nt] = pk2(s[nt][2], s[nt][3]);
        }
        // gather A-fragments: pa[k2] = P[query=cl][keys k2*32+q*8 .. +7]
        short8 pa[2];
        #pragma unroll
        for (int k2 = 0; k2 < 2; ++k2) {
            unsigned a0 = (unsigned)__shfl((int)p01[2*k2  ], src0);
            unsigned b0 = (unsigned)__shfl((int)p01[2*k2+1], src0);
            unsigned a1 = (unsigned)__shfl((int)p23[2*k2  ], src0);
            unsigned b1 = (unsigned)__shfl((int)p23[2*k2+1], src0);
            unsigned a2 = (unsigned)__shfl((int)p01[2*k2  ], src1);
            unsigned b2 = (unsigned)__shfl((int)p01[2*k2+1], src1);
            unsigned a3 = (unsigned)__shfl((int)p23[2*k2  ], src1);
            unsigned b3 = (unsigned)__shfl((int)p23[2*k2+1], src1);
            uint4v w;
            w[0] = hi ? b0 : a0;
            w[1] = hi ? b1 : a1;
            w[2] = hi ? b2 : a2;
            w[3] = hi ? b3 : a3;
            __builtin_memcpy(&pa[k2], &w, 16);
        }

        __builtin_amdgcn_s_setprio(1);
        #pragma unroll
        for (int n = 0; n < 8; ++n) {
            #pragma unroll
            for (int k2 = 0; k2 < 2; ++k2) {
                short8 vf = *(const short8*)&Vs[(n*16 + cl)*72 + k2*32 + q*8];
                o[n] = __builtin_amdgcn_mfma_f32_16x16x32_bf16(pa[k2], vf, o[n], 0, 0, 0);
            }
        }
        __builtin_amdgcn_s_setprio(0);
    }
    // reduce row-sums across the 4 q-group lanes holding the same query (cl)
    lsum += __shfl_xor(lsum, 16);
    lsum += __shfl_xor(lsum, 32);
    #pragma unroll
    for (int r = 0; r < 4; ++r) {
        float inv = 1.f / __shfl(lsum, q*4 + r);   // lane q*4+r holds query q*4+r's sum
        int row = i0 + m0 + q*4 + r;
        #pragma unroll
        for (int n = 0; n < 8; ++n)
            yb[(size_t)row*EMB + h*HD + n*16 + cl] = f2bs(o[n][r] * inv);
    }
}

// ---------------------------------------------------------------------------
extern "C" void kernel_launch(void* const* d_in, const int* in_sizes, int n_in,
                              void* d_out, int out_size, void* d_ws, size_t ws_size,
                              hipStream_t stream)
{
    const float* x    = (const float*)d_in[0];
    const float* ve   = (const float*)d_in[1];
    const float* cosb = (const float*)d_in[2];
    const float* sinb = (const float*)d_in[3];
    const float* wq   = (const float*)d_in[4];
    const float* wk   = (const float*)d_in[5];
    const float* wv   = (const float*)d_in[6];
    const float* wg   = (const float*)d_in[7];
    const float* wp   = (const float*)d_in[8];
    const int*   wsz  = (const int*)d_in[9];
    float* out = (float*)d_out;

    const size_t SEG = (size_t)T_SEQ * EMB;        // 4M elements = 8 MB bf16
    short* xb  = (short*)d_ws;                     // read only by qkv
    short* wbT = xb + SEG;                         // wq|wk|wv|wp transposed
    short* qb  = wbT + SEG;
    short* kb  = qb + SEG;
    short* vt  = kb + SEG;                         // 40 MB total
    short* yb  = xb;                               // alias: xb dead after qkv

    convert_all<<<dim3(64, 16, 5), 256, 0, stream>>>(wq, wk, wv, wp, x, wbT, xb);
    qkv_gemm_mfma<<<dim3(24, 32), 256, 0, stream>>>(xb, wbT, cosb, sinb,
                                                    x, ve, wg, qb, kb, vt);
    attn_flash<<<dim3(NH, T_SEQ/64), 256, 0, stream>>>((bf16*)qb, (bf16*)kb, (bf16*)vt, (bf16*)yb, wsz);
    proj_gemm_mfma<<<dim3(16, 32), 256, 0, stream>>>(yb, wbT + (size_t)3*EMB*EMB, out);
}